// Round 1
// baseline (669.795 us; speedup 1.0000x reference)
//
#include <hip/hip_runtime.h>

#define NE 500000
#define NB 256
#define D  128
#define ETILE 64
#define XPAD 132          // LDS row stride (f32) to break bank conflicts
#define APAD 8            // stride (u32) so each atomic counter sits on its own 32B
#define SCHUNK 1954       // ceil(NE/256)

__device__ __forceinline__ float lrelu(float x){ return x > 0.0f ? x : 0.01f * x; }

// monotonic float<->uint encoding for atomicMax on signed floats
__device__ __forceinline__ unsigned encf(float f){
  unsigned u = __float_as_uint(f);
  return (u & 0x80000000u) ? ~u : (u | 0x80000000u);
}
__device__ __forceinline__ float decf(unsigned u){
  return (u & 0x80000000u) ? __uint_as_float(u & 0x7fffffffu) : __uint_as_float(~u);
}

__global__ void k_init(unsigned* gmax, float* gsum, unsigned* hist){
  int t = threadIdx.x;
  if (t < NB){ gmax[t*APAD] = 0u; gsum[t*APAD] = 0.0f; hist[t*APAD] = 0u; }
}

// k = lrelu(u@Wk + bk); qu = u@Wq[128:] + bq; vu = u@Wv[128:] + bv
__global__ void k_pre(const float* __restrict__ u,  const float* __restrict__ Wq,
                      const float* __restrict__ bq, const float* __restrict__ Wk,
                      const float* __restrict__ bk, const float* __restrict__ Wv,
                      const float* __restrict__ bv,
                      float* __restrict__ kT, float* __restrict__ qu, float* __restrict__ vu){
  __shared__ float us[D];
  int b = blockIdx.x, c = threadIdx.x;
  us[c] = u[b*D + c];
  __syncthreads();
  float ka = bk[c], qa = bq[c], va = bv[c];
  #pragma unroll 4
  for (int j = 0; j < D; ++j){
    float uv = us[j];
    ka += uv * Wk[j*D + c];
    qa += uv * Wq[(D + j)*D + c];
    va += uv * Wv[(D + j)*D + c];
  }
  kT[b*D + c] = lrelu(ka);
  qu[b*D + c] = qa;
  vu[b*D + c] = va;
}

// scores[e] = lrelu(edges[e]@Wq[:128] + qu[eb]) . k[eb] / sqrt(128)
__global__ __launch_bounds__(256)
void k_score(const float* __restrict__ edges, const int* __restrict__ send,
             const int* __restrict__ batch, const float* __restrict__ Wq,
             const float* __restrict__ qu, const float* __restrict__ kT,
             float* __restrict__ scores, int* __restrict__ ebArr){
  __shared__ float xs[ETILE * XPAD];
  __shared__ int ebs[ETILE];
  const int tid  = threadIdx.x;
  const int base = blockIdx.x * ETILE;

  if (tid < ETILE){
    int e  = base + tid;
    int ec = e < NE ? e : NE - 1;
    int eb = batch[send[ec]];
    ebs[tid] = eb;
    if (e < NE) ebArr[e] = eb;
  }
  { // stage 64 edge rows (128 f32 each)
    int r = tid >> 2, q = tid & 3;
    int e = base + r; int ec = e < NE ? e : NE - 1;
    const float4* src = (const float4*)(edges + (size_t)ec * D + q * 32);
    float* drow = xs + r * XPAD + q * 32;
    #pragma unroll
    for (int c8 = 0; c8 < 8; ++c8) *(float4*)(drow + c8 * 4) = src[c8];
  }
  __syncthreads();

  const int cg = tid & 31, eg = tid >> 5;   // 4 cols x 8 edges per thread
  float4 acc[8];
  #pragma unroll
  for (int j = 0; j < 8; ++j) acc[j] = make_float4(0.f,0.f,0.f,0.f);
  const float* wp = Wq + 4 * cg;
  const float* xrow = xs + eg * 8 * XPAD;
  #pragma unroll 4
  for (int i = 0; i < D; ++i){
    float4 wv = *(const float4*)(wp + (size_t)i * D);
    #pragma unroll
    for (int j = 0; j < 8; ++j){
      float xv = xrow[j * XPAD + i];
      acc[j].x += xv * wv.x; acc[j].y += xv * wv.y;
      acc[j].z += xv * wv.z; acc[j].w += xv * wv.w;
    }
  }
  __syncthreads();   // done reading xs; reuse it for q values
  #pragma unroll
  for (int j = 0; j < 8; ++j){
    int er = eg * 8 + j;
    int eb = ebs[er];
    float4 quv = *(const float4*)(qu + (size_t)eb * D + 4 * cg);
    float4 qv;
    qv.x = lrelu(acc[j].x + quv.x);
    qv.y = lrelu(acc[j].y + quv.y);
    qv.z = lrelu(acc[j].z + quv.z);
    qv.w = lrelu(acc[j].w + quv.w);
    *(float4*)(xs + er * XPAD + 4 * cg) = qv;
  }
  __syncthreads();
  // per-edge dot with k[eb]: one wave handles 16 edges
  const int wv = tid >> 6, lane = tid & 63;
  for (int t = 0; t < 16; ++t){
    int er = wv * 16 + t;
    int eb = ebs[er];
    const float* krow = kT + (size_t)eb * D;
    float p = xs[er * XPAD + lane] * krow[lane]
            + xs[er * XPAD + 64 + lane] * krow[64 + lane];
    #pragma unroll
    for (int o = 32; o > 0; o >>= 1) p += __shfl_xor(p, o);
    int e = base + er;
    if (lane == 0 && e < NE) scores[e] = p * 0.08838834764831843f; // 1/sqrt(128)
  }
}

// per-graph max + count (LDS pre-aggregation, one block per ~1954 edges)
__global__ __launch_bounds__(256)
void k_stats(const float* __restrict__ scores, const int* __restrict__ ebArr,
             unsigned* gmax, unsigned* hist){
  __shared__ unsigned lmax[NB];
  __shared__ unsigned lcnt[NB];
  int tid = threadIdx.x;
  lmax[tid] = 0u; lcnt[tid] = 0u;
  __syncthreads();
  int start = blockIdx.x * SCHUNK;
  int end = start + SCHUNK; if (end > NE) end = NE;
  for (int e = start + tid; e < end; e += 256){
    int b = ebArr[e];
    atomicMax(&lmax[b], encf(scores[e]));
    atomicAdd(&lcnt[b], 1u);
  }
  __syncthreads();
  unsigned c = lcnt[tid];
  if (c){ atomicAdd(&hist[tid*APAD], c); atomicMax(&gmax[tid*APAD], lmax[tid]); }
}

__global__ void k_scan(const unsigned* __restrict__ hist, unsigned* __restrict__ offs,
                       unsigned* cursor){
  __shared__ unsigned sh[NB];
  __shared__ unsigned so[NB + 1];
  int tid = threadIdx.x;
  sh[tid] = hist[tid*APAD];
  __syncthreads();
  if (tid == 0){
    unsigned run = 0;
    for (int b = 0; b < NB; ++b){ so[b] = run; run += sh[b]; }
    so[NB] = run;
  }
  __syncthreads();
  offs[tid] = so[tid];
  cursor[tid*APAD] = so[tid];
  if (tid == 0) offs[NB] = so[NB];
}

// counting-sort scatter (block-batched) + per-graph sum of exp(score - max)
__global__ __launch_bounds__(256)
void k_scatter(const float* __restrict__ scores, const int* __restrict__ ebArr,
               const unsigned* __restrict__ gmax, unsigned* cursor,
               unsigned* __restrict__ perm, float* gsum){
  __shared__ unsigned lbase[NB];
  __shared__ unsigned lcnt[NB];
  __shared__ float lsum[NB];
  __shared__ float lgm[NB];
  int tid = threadIdx.x;
  lcnt[tid] = 0u; lsum[tid] = 0.0f; lgm[tid] = decf(gmax[tid*APAD]);
  __syncthreads();
  int start = blockIdx.x * SCHUNK;
  int end = start + SCHUNK; if (end > NE) end = NE;
  for (int e = start + tid; e < end; e += 256)
    atomicAdd(&lcnt[ebArr[e]], 1u);
  __syncthreads();
  unsigned c = lcnt[tid];
  lbase[tid] = c ? atomicAdd(&cursor[tid*APAD], c) : 0u;
  lcnt[tid] = 0u;
  __syncthreads();
  for (int e = start + tid; e < end; e += 256){
    int b = ebArr[e];
    unsigned p = lbase[b] + atomicAdd(&lcnt[b], 1u);
    perm[p] = (unsigned)e;
    atomicAdd(&lsum[b], __expf(scores[e] - lgm[b]));
  }
  __syncthreads();
  if (lsum[tid] != 0.0f) atomicAdd(&gsum[tid*APAD], lsum[tid]);
}

// per-graph: x[b] = sum_e w_e * lrelu(edges[e]@Wv[:128] + vu[b]) / gsum[b]
__global__ __launch_bounds__(256)
void k_accum(const float* __restrict__ edges, const float* __restrict__ Wv,
             const float* __restrict__ vu, const float* __restrict__ scores,
             const unsigned* __restrict__ gmax, const float* __restrict__ gsum,
             const unsigned* __restrict__ offs, const unsigned* __restrict__ perm,
             float* __restrict__ x){
  __shared__ float xs[ETILE * XPAD];
  __shared__ float wl[ETILE];
  __shared__ unsigned el[ETILE];
  const int b = blockIdx.x, tid = threadIdx.x;
  const unsigned o0 = offs[b], o1 = offs[b + 1];
  const int count = (int)(o1 - o0);
  if (count == 0){
    if (tid < D) x[(size_t)b * D + tid] = 0.0f;
    return;
  }
  const float gm = decf(gmax[b*APAD]);
  const int cg = tid & 31, eg = tid >> 5;
  const float4 vuv = *(const float4*)(vu + (size_t)b * D + 4 * cg);
  float4 xacc = make_float4(0.f,0.f,0.f,0.f);
  const int ntile = (count + ETILE - 1) / ETILE;
  for (int t = 0; t < ntile; ++t){
    __syncthreads();                      // previous tile fully consumed
    if (tid < ETILE){
      int slot = t * ETILE + tid;
      int sc = slot < count ? slot : count - 1;
      unsigned e = perm[o0 + sc];
      el[tid] = e;
      wl[tid] = (slot < count) ? __expf(scores[e] - gm) : 0.0f;
    }
    __syncthreads();
    {
      int r = tid >> 2, q = tid & 3;
      unsigned e = el[r];
      const float4* src = (const float4*)(edges + (size_t)e * D + q * 32);
      float* drow = xs + r * XPAD + q * 32;
      #pragma unroll
      for (int c8 = 0; c8 < 8; ++c8) *(float4*)(drow + c8 * 4) = src[c8];
    }
    __syncthreads();
    float4 acc[8];
    #pragma unroll
    for (int j = 0; j < 8; ++j) acc[j] = make_float4(0.f,0.f,0.f,0.f);
    const float* wp = Wv + 4 * cg;
    const float* xrow = xs + eg * 8 * XPAD;
    #pragma unroll 4
    for (int i = 0; i < D; ++i){
      float4 wv4 = *(const float4*)(wp + (size_t)i * D);
      #pragma unroll
      for (int j = 0; j < 8; ++j){
        float xv = xrow[j * XPAD + i];
        acc[j].x += xv * wv4.x; acc[j].y += xv * wv4.y;
        acc[j].z += xv * wv4.z; acc[j].w += xv * wv4.w;
      }
    }
    #pragma unroll
    for (int j = 0; j < 8; ++j){
      float we = wl[eg * 8 + j];
      xacc.x += we * lrelu(acc[j].x + vuv.x);
      xacc.y += we * lrelu(acc[j].y + vuv.y);
      xacc.z += we * lrelu(acc[j].z + vuv.z);
      xacc.w += we * lrelu(acc[j].w + vuv.w);
    }
  }
  __syncthreads();
  *(float4*)(xs + eg * XPAD + 4 * cg) = xacc;   // 8 partial rows of 128
  __syncthreads();
  if (tid < D){
    float s = 0.0f;
    #pragma unroll
    for (int g = 0; g < 8; ++g) s += xs[g * XPAD + tid];
    float gs = gsum[b*APAD];
    x[(size_t)b * D + tid] = gs > 0.0f ? s / gs : 0.0f;
  }
}

__global__ void k_final(const float* __restrict__ x, const float* __restrict__ Wl,
                        const float* __restrict__ bl, float* __restrict__ out){
  __shared__ float xr[D];
  int b = blockIdx.x, c = threadIdx.x;
  xr[c] = x[(size_t)b * D + c];
  __syncthreads();
  float a = bl[c];
  #pragma unroll 4
  for (int j = 0; j < D; ++j) a += xr[j] * Wl[j*D + c];
  out[(size_t)b * D + c] = lrelu(a);
}

extern "C" void kernel_launch(void* const* d_in, const int* in_sizes, int n_in,
                              void* d_out, int out_size, void* d_ws, size_t ws_size,
                              hipStream_t stream){
  // setup_inputs order: nodes, edges, edge_index, u, batch, Wq, bq, Wk, bk, Wv, bv, Wl, bl
  const float* edges = (const float*)d_in[1];
  const int*   send  = (const int*)d_in[2];      // edge_index[0] = first NE ints
  const float* u     = (const float*)d_in[3];
  const int*   batch = (const int*)d_in[4];
  const float* Wq    = (const float*)d_in[5];
  const float* bq    = (const float*)d_in[6];
  const float* Wk    = (const float*)d_in[7];
  const float* bk    = (const float*)d_in[8];
  const float* Wv    = (const float*)d_in[9];
  const float* bv    = (const float*)d_in[10];
  const float* Wl    = (const float*)d_in[11];
  const float* bl    = (const float*)d_in[12];
  float* out = (float*)d_out;

  char* wsb = (char*)d_ws;
  size_t off = 0;
  auto alloc = [&](size_t bytes)->char*{
    char* p = wsb + off; off += (bytes + 255) & ~(size_t)255; return p;
  };
  float*    kT     = (float*)   alloc((size_t)NB * D * 4);
  float*    qu     = (float*)   alloc((size_t)NB * D * 4);
  float*    vu     = (float*)   alloc((size_t)NB * D * 4);
  float*    x      = (float*)   alloc((size_t)NB * D * 4);
  unsigned* gmax   = (unsigned*)alloc((size_t)NB * APAD * 4);
  float*    gsum   = (float*)   alloc((size_t)NB * APAD * 4);
  unsigned* hist   = (unsigned*)alloc((size_t)NB * APAD * 4);
  unsigned* cursor = (unsigned*)alloc((size_t)NB * APAD * 4);
  unsigned* offs   = (unsigned*)alloc((size_t)(NB + 1) * 4);
  float*    scores = (float*)   alloc((size_t)NE * 4);
  int*      ebArr  = (int*)     alloc((size_t)NE * 4);
  unsigned* perm   = (unsigned*)alloc((size_t)NE * 4);
  (void)ws_size; (void)in_sizes; (void)n_in; (void)out_size;

  k_init   <<<1, 256, 0, stream>>>(gmax, gsum, hist);
  k_pre    <<<NB, D, 0, stream>>>(u, Wq, bq, Wk, bk, Wv, bv, kT, qu, vu);
  k_score  <<<(NE + ETILE - 1) / ETILE, 256, 0, stream>>>(edges, send, batch, Wq, qu, kT, scores, ebArr);
  k_stats  <<<256, 256, 0, stream>>>(scores, ebArr, gmax, hist);
  k_scan   <<<1, 256, 0, stream>>>(hist, offs, cursor);
  k_scatter<<<256, 256, 0, stream>>>(scores, ebArr, gmax, cursor, perm, gsum);
  k_accum  <<<NB, 256, 0, stream>>>(edges, Wv, vu, scores, gmax, gsum, offs, perm, x);
  k_final  <<<NB, D, 0, stream>>>(x, Wl, bl, out);
}

// Round 3
// 202.027 us; speedup vs baseline: 3.3154x; 3.3154x over previous
//
#include <hip/hip_runtime.h>

#define NE 500000
#define NB 256
#define D  128
#define NT 7813           // ceil(NE/64)
#define GS 2048           // grid for k_score
#define SPLIT 8           // chunks per graph in k_accum
#define APAD 8            // stride (u32) so each atomic counter sits on its own 32B
#define SCHUNK 1954       // ceil(NE/256)

typedef __attribute__((ext_vector_type(8))) short bf16x8;
typedef __attribute__((ext_vector_type(4))) float f32x4;

__device__ __forceinline__ float lrelu(float x){ return x > 0.0f ? x : 0.01f * x; }

// f32 -> bf16 (round-to-nearest-even), header-free
__device__ __forceinline__ unsigned short f2bf(float f){
  unsigned u = __float_as_uint(f);
  unsigned rounding = 0x7fffu + ((u >> 16) & 1u);
  return (unsigned short)((u + rounding) >> 16);
}

// monotonic float<->uint encoding for atomicMax on signed floats
__device__ __forceinline__ unsigned encf(float f){
  unsigned u = __float_as_uint(f);
  return (u & 0x80000000u) ? ~u : (u | 0x80000000u);
}
__device__ __forceinline__ float decf(unsigned u){
  return (u & 0x80000000u) ? __uint_as_float(u & 0x7fffffffu) : __uint_as_float(~u);
}

__global__ void k_init(unsigned* gmax, float* gsum, unsigned* hist){
  int t = threadIdx.x;
  if (t < NB){ gmax[t*APAD] = 0u; gsum[t*APAD] = 0.0f; hist[t*APAD] = 0u; }
}

// k = lrelu(u@Wk + bk); qu = u@Wq[128:] + bq; vu = u@Wv[128:] + bv
__global__ void k_pre(const float* __restrict__ u,  const float* __restrict__ Wq,
                      const float* __restrict__ bq, const float* __restrict__ Wk,
                      const float* __restrict__ bk, const float* __restrict__ Wv,
                      const float* __restrict__ bv,
                      float* __restrict__ kT, float* __restrict__ qu, float* __restrict__ vu){
  __shared__ float us[D];
  int b = blockIdx.x, c = threadIdx.x;
  us[c] = u[b*D + c];
  __syncthreads();
  float ka = bk[c], qa = bq[c], va = bv[c];
  #pragma unroll 4
  for (int j = 0; j < D; ++j){
    float uv = us[j];
    ka += uv * Wk[j*D + c];
    qa += uv * Wq[(D + j)*D + c];
    va += uv * Wv[(D + j)*D + c];
  }
  kT[b*D + c] = lrelu(ka);
  qu[b*D + c] = qa;
  vu[b*D + c] = va;
}

// WqT/WvT[c][k] = bf16(W[k][c]) for k<128 (edge half of the weight)
__global__ void k_prew(const float* __restrict__ Wq, const float* __restrict__ Wv,
                       unsigned short* __restrict__ WqT, unsigned short* __restrict__ WvT){
  int c = blockIdx.x, k = threadIdx.x;
  WqT[c*D + k] = f2bf(Wq[k*D + c]);
  WvT[c*D + k] = f2bf(Wv[k*D + c]);
}

// ---- shared MFMA helpers (LDS layout: row-major, 256B rows, 16B-chunk XOR swizzle) ----
__device__ __forceinline__ void stage_weights(unsigned short* wt, const unsigned short* Wsrc, int tid){
  const uint4* wsrc = (const uint4*)Wsrc;      // 128x128 bf16 = 2048 uint4
  for (int i = tid; i < 2048; i += 256){
    int c = i >> 4, off = (i & 15) << 4;
    *(uint4*)((char*)wt + c*256 + (off ^ ((c & 7) << 4))) = wsrc[i];
  }
}

__device__ __forceinline__ void stage_edge_row(unsigned short* xs, const float* __restrict__ edges,
                                               long e, int r, int q){
  const float4* src = (const float4*)(edges + (size_t)e * D + q * 32);
  char* xrow = (char*)xs + r * 256;
  #pragma unroll
  for (int ci = 0; ci < 4; ++ci){
    float4 a = src[2*ci], b = src[2*ci + 1];
    bf16x8 pk;
    pk[0] = (short)f2bf(a.x); pk[1] = (short)f2bf(a.y);
    pk[2] = (short)f2bf(a.z); pk[3] = (short)f2bf(a.w);
    pk[4] = (short)f2bf(b.x); pk[5] = (short)f2bf(b.y);
    pk[6] = (short)f2bf(b.z); pk[7] = (short)f2bf(b.w);
    int off = q * 64 + ci * 16;
    *(bf16x8*)(xrow + (off ^ ((r & 7) << 4))) = pk;
  }
}

// per-wave: 16 rows (16w..16w+15) x 128 cols, K=128.  acc must be pre-initialized (bias).
__device__ __forceinline__ void mfma_tile(f32x4 acc[8], const unsigned short* xs,
                                          const unsigned short* wt, int w, int g, int m){
  const int arow = 16 * w + m;
  #pragma unroll
  for (int ks = 0; ks < 4; ++ks){
    int koff = ks * 64 + (g << 4);
    bf16x8 af = *(const bf16x8*)((const char*)xs + arow*256 + (koff ^ ((arow & 7) << 4)));
    #pragma unroll
    for (int n = 0; n < 8; ++n){
      int bc = 16 * n + m;
      bf16x8 bv = *(const bf16x8*)((const char*)wt + bc*256 + (koff ^ ((bc & 7) << 4)));
      acc[n] = __builtin_amdgcn_mfma_f32_16x16x32_bf16(af, bv, acc[n], 0, 0, 0);
    }
  }
}

// scores[e] = lrelu(edges[e]@Wq[:128] + qu[eb]) . k[eb] / sqrt(128)
__global__ __launch_bounds__(256)
void k_score(const float* __restrict__ edges, const int* __restrict__ send,
             const int* __restrict__ batch, const unsigned short* __restrict__ WqT,
             const float* __restrict__ qu, const float* __restrict__ kT,
             float* __restrict__ scores, int* __restrict__ ebArr){
  __shared__ __align__(16) unsigned short wt[D * D];
  __shared__ __align__(16) unsigned short xs[64 * D];
  __shared__ int ebs[64];
  const int tid = threadIdx.x;
  stage_weights(wt, WqT, tid);
  const int lane = tid & 63, w = tid >> 6, g = lane >> 4, m = lane & 15;
  const int r = tid >> 2, q = tid & 3;

  for (int t = blockIdx.x; t < NT; t += GS){
    __syncthreads();                      // previous tile fully consumed (also covers wt stage)
    const int base = t * 64;
    if (tid < 64){
      int e  = base + tid;
      int ec = e < NE ? e : NE - 1;
      int eb = batch[send[ec]];
      ebs[tid] = eb;
      if (e < NE) ebArr[e] = eb;
    }
    {
      int e = base + r; if (e >= NE) e = NE - 1;
      stage_edge_row(xs, edges, e, r, q);
    }
    __syncthreads();

    int ebj[4];
    #pragma unroll
    for (int j = 0; j < 4; ++j) ebj[j] = ebs[16*w + 4*g + j];
    f32x4 acc[8];
    #pragma unroll
    for (int n = 0; n < 8; ++n){
      #pragma unroll
      for (int j = 0; j < 4; ++j)
        acc[n][j] = qu[(size_t)ebj[j] * D + 16*n + m];   // bias as MFMA C-in
    }
    mfma_tile(acc, xs, wt, w, g, m);

    #pragma unroll
    for (int j = 0; j < 4; ++j){
      float p = 0.0f;
      const float* krow = kT + (size_t)ebj[j] * D;
      #pragma unroll
      for (int n = 0; n < 8; ++n)
        p += lrelu(acc[n][j]) * krow[16*n + m];
      p += __shfl_xor(p, 1); p += __shfl_xor(p, 2);
      p += __shfl_xor(p, 4); p += __shfl_xor(p, 8);
      int eg = base + 16*w + 4*g + j;
      if (m == 0 && eg < NE) scores[eg] = p * 0.08838834764831843f;
    }
  }
}

// per-graph max + count (LDS pre-aggregation)
__global__ __launch_bounds__(256)
void k_stats(const float* __restrict__ scores, const int* __restrict__ ebArr,
             unsigned* gmax, unsigned* hist){
  __shared__ unsigned lmax[NB];
  __shared__ unsigned lcnt[NB];
  int tid = threadIdx.x;
  lmax[tid] = 0u; lcnt[tid] = 0u;
  __syncthreads();
  int start = blockIdx.x * SCHUNK;
  int end = start + SCHUNK; if (end > NE) end = NE;
  for (int e = start + tid; e < end; e += 256){
    int b = ebArr[e];
    atomicMax(&lmax[b], encf(scores[e]));
    atomicAdd(&lcnt[b], 1u);
  }
  __syncthreads();
  unsigned c = lcnt[tid];
  if (c){ atomicAdd(&hist[tid*APAD], c); atomicMax(&gmax[tid*APAD], lmax[tid]); }
}

__global__ void k_scan(const unsigned* __restrict__ hist, unsigned* __restrict__ offs,
                       unsigned* cursor){
  __shared__ unsigned sh[NB];
  __shared__ unsigned so[NB + 1];
  int tid = threadIdx.x;
  sh[tid] = hist[tid*APAD];
  __syncthreads();
  if (tid == 0){
    unsigned run = 0;
    for (int b = 0; b < NB; ++b){ so[b] = run; run += sh[b]; }
    so[NB] = run;
  }
  __syncthreads();
  offs[tid] = so[tid];
  cursor[tid*APAD] = so[tid];
  if (tid == 0) offs[NB] = so[NB];
}

// counting-sort scatter (block-batched) + per-graph sum of exp(score - max)
__global__ __launch_bounds__(256)
void k_scatter(const float* __restrict__ scores, const int* __restrict__ ebArr,
               const unsigned* __restrict__ gmax, unsigned* cursor,
               unsigned* __restrict__ perm, float* gsum){
  __shared__ unsigned lbase[NB];
  __shared__ unsigned lcnt[NB];
  __shared__ float lsum[NB];
  __shared__ float lgm[NB];
  int tid = threadIdx.x;
  lcnt[tid] = 0u; lsum[tid] = 0.0f; lgm[tid] = decf(gmax[tid*APAD]);
  __syncthreads();
  int start = blockIdx.x * SCHUNK;
  int end = start + SCHUNK; if (end > NE) end = NE;
  for (int e = start + tid; e < end; e += 256)
    atomicAdd(&lcnt[ebArr[e]], 1u);
  __syncthreads();
  unsigned c = lcnt[tid];
  lbase[tid] = c ? atomicAdd(&cursor[tid*APAD], c) : 0u;
  lcnt[tid] = 0u;
  __syncthreads();
  for (int e = start + tid; e < end; e += 256){
    int b = ebArr[e];
    unsigned p = lbase[b] + atomicAdd(&lcnt[b], 1u);
    perm[p] = (unsigned)e;
    atomicAdd(&lsum[b], __expf(scores[e] - lgm[b]));
  }
  __syncthreads();
  if (lsum[tid] != 0.0f) atomicAdd(&gsum[tid*APAD], lsum[tid]);
}

// per-(graph,chunk): xpart[b][ch] = sum_{e in chunk} w_e * lrelu(edges[e]@Wv[:128] + vu[b])
__global__ __launch_bounds__(256)
void k_accum(const float* __restrict__ edges, const unsigned short* __restrict__ WvT,
             const float* __restrict__ vu, const float* __restrict__ scores,
             const unsigned* __restrict__ gmax, const unsigned* __restrict__ offs,
             const unsigned* __restrict__ perm, float* __restrict__ xpart){
  __shared__ __align__(16) unsigned short wt[D * D];
  __shared__ __align__(16) unsigned short xs[64 * D];
  __shared__ float wlds[64];
  __shared__ unsigned el[64];
  __shared__ float xred[4 * D];
  const int tid = threadIdx.x;
  const int b = blockIdx.x >> 3, chunk = blockIdx.x & (SPLIT - 1);
  const unsigned o0 = offs[b];
  const int count = (int)(offs[b + 1] - o0);
  stage_weights(wt, WvT, tid);
  const float gm = decf(gmax[b*APAD]);
  const int lane = tid & 63, w = tid >> 6, g = lane >> 4, m = lane & 15;
  const int r = tid >> 2, q = tid & 3;
  float vureg[8];
  #pragma unroll
  for (int n = 0; n < 8; ++n) vureg[n] = vu[(size_t)b * D + 16*n + m];
  float xacc[8] = {0,0,0,0,0,0,0,0};

  const int ntile = (count + 63) >> 6;
  for (int t = chunk; t < ntile; t += SPLIT){
    __syncthreads();                       // previous tile fully consumed
    if (tid < 64){
      int slot = t * 64 + tid;
      int sc_ = slot < count ? slot : count - 1;
      unsigned e = perm[o0 + sc_];
      el[tid] = e;
      wlds[tid] = slot < count ? __expf(scores[e] - gm) : 0.0f;
    }
    __syncthreads();
    stage_edge_row(xs, edges, (long)el[r], r, q);
    __syncthreads();

    f32x4 acc[8];
    #pragma unroll
    for (int n = 0; n < 8; ++n){
      acc[n][0] = vureg[n]; acc[n][1] = vureg[n];
      acc[n][2] = vureg[n]; acc[n][3] = vureg[n];   // bias as MFMA C-in
    }
    mfma_tile(acc, xs, wt, w, g, m);

    #pragma unroll
    for (int j = 0; j < 4; ++j){
      float wlj = wlds[16*w + 4*g + j];
      #pragma unroll
      for (int n = 0; n < 8; ++n)
        xacc[n] += wlj * lrelu(acc[n][j]);
    }
  }
  // reduce: across lane groups (rows) then across waves
  #pragma unroll
  for (int n = 0; n < 8; ++n){
    float v = xacc[n];
    v += __shfl_xor(v, 16);
    v += __shfl_xor(v, 32);
    if (g == 0) xred[w * D + 16*n + m] = v;
  }
  __syncthreads();
  if (tid < D){
    float s = xred[tid] + xred[D + tid] + xred[2*D + tid] + xred[3*D + tid];
    xpart[((size_t)b * SPLIT + chunk) * D + tid] = s;
  }
}

__global__ void k_final(const float* __restrict__ xpart, const float* __restrict__ gsum,
                        const float* __restrict__ Wl, const float* __restrict__ bl,
                        float* __restrict__ out){
  __shared__ float xr[D];
  int b = blockIdx.x, c = threadIdx.x;
  float gs = gsum[b*APAD];
  float s = 0.0f;
  #pragma unroll
  for (int ch = 0; ch < SPLIT; ++ch) s += xpart[((size_t)b * SPLIT + ch) * D + c];
  xr[c] = gs > 0.0f ? s / gs : 0.0f;
  __syncthreads();
  float a = bl[c];
  #pragma unroll 4
  for (int j = 0; j < D; ++j) a += xr[j] * Wl[j*D + c];
  out[(size_t)b * D + c] = lrelu(a);
}

extern "C" void kernel_launch(void* const* d_in, const int* in_sizes, int n_in,
                              void* d_out, int out_size, void* d_ws, size_t ws_size,
                              hipStream_t stream){
  // setup_inputs order: nodes, edges, edge_index, u, batch, Wq, bq, Wk, bk, Wv, bv, Wl, bl
  const float* edges = (const float*)d_in[1];
  const int*   send  = (const int*)d_in[2];      // edge_index[0] = first NE ints
  const float* u     = (const float*)d_in[3];
  const int*   batch = (const int*)d_in[4];
  const float* Wq    = (const float*)d_in[5];
  const float* bq    = (const float*)d_in[6];
  const float* Wk    = (const float*)d_in[7];
  const float* bk    = (const float*)d_in[8];
  const float* Wv    = (const float*)d_in[9];
  const float* bv    = (const float*)d_in[10];
  const float* Wl    = (const float*)d_in[11];
  const float* bl    = (const float*)d_in[12];
  float* out = (float*)d_out;

  char* wsb = (char*)d_ws;
  size_t off = 0;
  auto alloc = [&](size_t bytes)->char*{
    char* p = wsb + off; off += (bytes + 255) & ~(size_t)255; return p;
  };
  float*    kT     = (float*)   alloc((size_t)NB * D * 4);
  float*    qu     = (float*)   alloc((size_t)NB * D * 4);
  float*    vu     = (float*)   alloc((size_t)NB * D * 4);
  unsigned* gmax   = (unsigned*)alloc((size_t)NB * APAD * 4);
  float*    gsum   = (float*)   alloc((size_t)NB * APAD * 4);
  unsigned* hist   = (unsigned*)alloc((size_t)NB * APAD * 4);
  unsigned* cursor = (unsigned*)alloc((size_t)NB * APAD * 4);
  unsigned* offs   = (unsigned*)alloc((size_t)(NB + 1) * 4);
  unsigned short* WqTb = (unsigned short*)alloc((size_t)D * D * 2);
  unsigned short* WvTb = (unsigned short*)alloc((size_t)D * D * 2);
  float*    xpart  = (float*)   alloc((size_t)NB * SPLIT * D * 4);
  float*    scores = (float*)   alloc((size_t)NE * 4);
  int*      ebArr  = (int*)     alloc((size_t)NE * 4);
  unsigned* perm   = (unsigned*)alloc((size_t)NE * 4);
  (void)ws_size; (void)in_sizes; (void)n_in; (void)out_size;

  k_init   <<<1, 256, 0, stream>>>(gmax, gsum, hist);
  k_pre    <<<NB, D, 0, stream>>>(u, Wq, bq, Wk, bk, Wv, bv, kT, qu, vu);
  k_prew   <<<D, D, 0, stream>>>(Wq, Wv, WqTb, WvTb);
  k_score  <<<GS, 256, 0, stream>>>(edges, send, batch, WqTb, qu, kT, scores, ebArr);
  k_stats  <<<256, 256, 0, stream>>>(scores, ebArr, gmax, hist);
  k_scan   <<<1, 256, 0, stream>>>(hist, offs, cursor);
  k_scatter<<<256, 256, 0, stream>>>(scores, ebArr, gmax, cursor, perm, gsum);
  k_accum  <<<NB * SPLIT, 256, 0, stream>>>(edges, WvTb, vu, scores, gmax, offs, perm, xpart);
  k_final  <<<NB, D, 0, stream>>>(xpart, gsum, Wl, bl, out);
}